// Round 8
// baseline (180.419 us; speedup 1.0000x reference)
//
#include <hip/hip_runtime.h>
#include <stdint.h>

#define NB 4
#define NT 2048
#define ND 512
#define NH 8
#define NDK 64
#define NM (NB*NT)   // 8192 rows

typedef __attribute__((ext_vector_type(8))) short short8;
typedef __attribute__((ext_vector_type(4))) short bs4;     // 4 bf16 (2 VGPR)
typedef __attribute__((ext_vector_type(4))) float f32x4;

// round-to-nearest-even fp32 -> bf16
__device__ __forceinline__ unsigned short f2b(float f) {
    union { float f; uint32_t u; } v; v.f = f;
    return (unsigned short)((v.u + 0x7FFFu + ((v.u >> 16) & 1u)) >> 16);
}

__device__ __forceinline__ void load_lds16(const void* g, void* l) {
    void* gn = const_cast<void*>(g);
    __builtin_amdgcn_global_load_lds((__attribute__((address_space(1))) void*)gn,
                                     (__attribute__((address_space(3))) void*)l,
                                     16, 0, 0);
}

// ---------------------------------------------------------------------------
// fp32 -> bf16 conversion of x + Wq,Wk,Wv,Wo, packed into ws.
// ---------------------------------------------------------------------------
__global__ void convert_all(const float* __restrict__ x,  const float* __restrict__ wq,
                            const float* __restrict__ wk, const float* __restrict__ wv,
                            const float* __restrict__ wo, unsigned short* __restrict__ dst) {
    size_t i = ((size_t)blockIdx.x * 256 + threadIdx.x) * 4;
    const float* src; size_t off;
    if (i < 4194304) { src = x; off = i; }
    else {
        size_t j = i - 4194304;
        src = (j < 262144) ? wq : (j < 524288) ? wk : (j < 786432) ? wv : wo;
        off = j & 262143;
    }
    f32x4 v = *(const f32x4*)(src + off);
    ushort4 r;
    r.x = f2b(v[0]); r.y = f2b(v[1]); r.z = f2b(v[2]); r.w = f2b(v[3]);
    *(ushort4*)(dst + i) = r;
}

// ---------------------------------------------------------------------------
// Projections. z=0: Q = x@Wq.T (scaled), z=1: K = x@Wk.T  -> row-major bf16.
// z=2: VT = Wv@x.T directly -> VT[(b*8+h)*64+d][t], coalesced along t.
// m97 structure: 128x128 tile, BK=32, 256 thr, global_load_lds staging.
// ---------------------------------------------------------------------------
__global__ __launch_bounds__(256, 3) void proj_gemm(
        const unsigned short* __restrict__ X,
        const unsigned short* __restrict__ Wbase,
        const float* __restrict__ bias0, const float* __restrict__ bias1,
        const float* __restrict__ bias2,
        unsigned short* __restrict__ Obase, unsigned short* __restrict__ VTb,
        float scale0) {
    const int z = blockIdx.z;
    const float* bias = (z == 0) ? bias0 : (z == 1 ? bias1 : bias2);
    const float scale = (z == 0) ? scale0 : 1.0f;

    int rowBase, colBase;
    const unsigned short *Ap, *Bp;
    if (z == 2) {   // A = Wv (rows=d), B = x (rows=t)
        rowBase = blockIdx.x * 128;  colBase = blockIdx.y * 128;
        Ap = Wbase + 2 * (ND * ND);  Bp = X;
    } else {        // A = x (rows=t), B = Wq/Wk (rows=d)
        rowBase = blockIdx.y * 128;  colBase = blockIdx.x * 128;
        Ap = X;                      Bp = Wbase + (size_t)z * (ND * ND);
    }

    __shared__ alignas(16) unsigned short ldsA[128 * 32];
    __shared__ alignas(16) unsigned short ldsW[128 * 32];

    const int tid = threadIdx.x;
    const int lane = tid & 63, wave = tid >> 6;
    const int quad = lane >> 4, l15 = lane & 15;
    const int wm = wave >> 1, wn = wave & 1;

    const int rS = wave * 16 + (lane >> 2);
    const int kS = (lane & 3) * 8;
    const unsigned short* gA = Ap + (size_t)(rowBase + rS) * ND + kS;
    const unsigned short* gW = Bp + (size_t)(colBase + rS) * ND + kS;
    unsigned short* lA = ldsA + wave * 512;
    unsigned short* lW = ldsW + wave * 512;

    f32x4 acc[4][4];
#pragma unroll
    for (int i = 0; i < 4; i++)
#pragma unroll
        for (int j = 0; j < 4; j++) acc[i][j] = (f32x4)0.0f;

    for (int kt = 0; kt < ND / 32; ++kt) {
        __syncthreads();
        load_lds16(gA,            lA);
        load_lds16(gA + 64 * ND,  lA + 2048);
        load_lds16(gW,            lW);
        load_lds16(gW + 64 * ND,  lW + 2048);
        gA += 32; gW += 32;
        __syncthreads();

        short8 af[4], bfm[4];
#pragma unroll
        for (int mt = 0; mt < 4; ++mt)
            af[mt] = *(const short8*)(ldsA + (wm * 64 + mt * 16 + l15) * 32 + quad * 8);
#pragma unroll
        for (int nt = 0; nt < 4; ++nt)
            bfm[nt] = *(const short8*)(ldsW + (wn * 64 + nt * 16 + l15) * 32 + quad * 8);
#pragma unroll
        for (int mt = 0; mt < 4; ++mt)
#pragma unroll
            for (int nt = 0; nt < 4; ++nt)
                acc[mt][nt] = __builtin_amdgcn_mfma_f32_16x16x32_bf16(
                    af[mt], bfm[nt], acc[mt][nt], 0, 0, 0);
    }

    if (z == 2) {
        const int bz = colBase >> 11;
        const int t0 = colBase & 2047;
        unsigned short* VTo = VTb + ((size_t)(bz * 512 + rowBase)) * NT + t0;
#pragma unroll
        for (int mt = 0; mt < 4; mt++)
#pragma unroll
            for (int reg = 0; reg < 4; reg++) {
                int m = wm * 64 + mt * 16 + quad * 4 + reg;
                float bm = bias[rowBase + m];
                unsigned short* dst = VTo + (size_t)m * NT + wn * 64 + l15;
#pragma unroll
                for (int nt = 0; nt < 4; nt++)
                    dst[nt * 16] = f2b(acc[mt][nt][reg] + bm);
            }
    } else {
        float biasr[4];
#pragma unroll
        for (int nt = 0; nt < 4; nt++)
            biasr[nt] = bias[colBase + wn * 64 + nt * 16 + l15];
        unsigned short* Oz = Obase + (size_t)z * ((size_t)NM * ND);
#pragma unroll
        for (int mt = 0; mt < 4; mt++) {
            int row = rowBase + wm * 64 + mt * 16 + quad * 4;
#pragma unroll
            for (int reg = 0; reg < 4; reg++) {
                unsigned short* dst = Oz + (size_t)(row + reg) * ND + colBase + wn * 64 + l15;
#pragma unroll
                for (int nt = 0; nt < 4; nt++)
                    dst[nt * 16] = f2b((acc[mt][nt][reg] + biasr[nt]) * scale);
            }
        }
    }
}

// ---------------------------------------------------------------------------
// Output projection (fp32 out): 64x128 tile, 2x2 wave grid (32x64 per wave)
// -> 6 LDS reads per 8 MFMA per wave-iter. grid (4, 128) = 512 blocks.
// ---------------------------------------------------------------------------
__global__ __launch_bounds__(256, 4) void out_gemm(
        const unsigned short* __restrict__ A, const unsigned short* __restrict__ W,
        const float* __restrict__ bias, float* __restrict__ OF) {
    __shared__ alignas(16) unsigned short ldsA[64 * 32];
    __shared__ alignas(16) unsigned short ldsW[128 * 32];

    const int tid = threadIdx.x;
    const int lane = tid & 63, wave = tid >> 6;
    const int quad = lane >> 4, l15 = lane & 15;
    const int wm = wave >> 1, wn = wave & 1;
    const int rowBase = blockIdx.y * 64;
    const int colBase = blockIdx.x * 128;

    const int rW = wave * 16 + (lane >> 2);
    const int kS = (lane & 3) * 8;
    const unsigned short* gA = A + (size_t)(rowBase + rW) * ND + kS;
    const unsigned short* gW = W + (size_t)(colBase + rW) * ND + kS;
    unsigned short* lA = ldsA + wave * 512;
    unsigned short* lW = ldsW + wave * 512;

    f32x4 acc[2][4];
#pragma unroll
    for (int mt = 0; mt < 2; mt++)
#pragma unroll
        for (int nt = 0; nt < 4; nt++) acc[mt][nt] = (f32x4)0.0f;

    for (int kt = 0; kt < ND / 32; ++kt) {
        __syncthreads();
        load_lds16(gA,           lA);
        load_lds16(gW,           lW);
        load_lds16(gW + 64 * ND, lW + 2048);
        gA += 32; gW += 32;
        __syncthreads();

        short8 af[2], bfm[4];
#pragma unroll
        for (int mt = 0; mt < 2; ++mt)
            af[mt] = *(const short8*)(ldsA + (wm * 32 + mt * 16 + l15) * 32 + quad * 8);
#pragma unroll
        for (int nt = 0; nt < 4; ++nt)
            bfm[nt] = *(const short8*)(ldsW + (wn * 64 + nt * 16 + l15) * 32 + quad * 8);
#pragma unroll
        for (int mt = 0; mt < 2; ++mt)
#pragma unroll
            for (int nt = 0; nt < 4; ++nt)
                acc[mt][nt] = __builtin_amdgcn_mfma_f32_16x16x32_bf16(
                    af[mt], bfm[nt], acc[mt][nt], 0, 0, 0);
    }

    float biasr[4];
#pragma unroll
    for (int nt = 0; nt < 4; nt++)
        biasr[nt] = bias[colBase + wn * 64 + nt * 16 + l15];

#pragma unroll
    for (int mt = 0; mt < 2; mt++)
#pragma unroll
        for (int reg = 0; reg < 4; reg++) {
            int row = rowBase + wm * 32 + mt * 16 + quad * 4 + reg;
            float* dst = OF + (size_t)row * ND + colBase + wn * 64 + l15;
#pragma unroll
            for (int nt = 0; nt < 4; nt++)
                dst[nt * 16] = acc[mt][nt][reg] + biasr[nt];
        }
}

// ---------------------------------------------------------------------------
// Flash attention v7 — single-barrier double-buffered pipeline.
// grid (32,8,4)=1024 blocks (4/CU), 256 thr; wave w owns q-rows [w*16,w*16+16)
// x all 64 keys. XOR-swizzled chunk layout (v6): LDS chunk (r,p) holds global
// chunk p^(r&7); DMA deposits contiguous (zero write conflicts).
// Loop: { barrier (drains DMA issued LAST iter -> ~free); issue DMA kv+1
// into other buffer; compute kv }. DMA has the whole compute phase to land.
// S^T trick keeps P in registers (v5).
// ---------------------------------------------------------------------------
__global__ __launch_bounds__(256, 4) void attn_kernel(
        const unsigned short* __restrict__ Qb, const unsigned short* __restrict__ Kb,
        const unsigned short* __restrict__ VTb, unsigned short* __restrict__ Cb) {
    const int qt = blockIdx.x, h = blockIdx.y, b = blockIdx.z;
    __shared__ alignas(16) unsigned short Ks[2 * 64 * 64];   // 16 KB
    __shared__ alignas(16) unsigned short Vt[2 * 64 * 64];   // 16 KB

    const int tid = threadIdx.x, lane = tid & 63, wave = tid >> 6;
    const int quad = lane >> 4, l15 = lane & 15;
    const size_t headOff = (size_t)h * NDK;
    const size_t rowB = (size_t)b * NT;
    const unsigned short* VT = VTb + (size_t)(b * NH + h) * ((size_t)NDK * NT);

    // Q fragments (B-operand of S^T MFMA): lane holds Q[q=l15][k=quad*8+j]
    short8 aq[2];
#pragma unroll
    for (int ks = 0; ks < 2; ++ks)
        aq[ks] = *(const short8*)(Qb + (rowB + qt * 64 + wave * 16 + l15) * ND
                                  + headOff + ks * 32 + quad * 8);

    // staging lane constants: call c covers rows wave*16+c*8+(lane>>3)
    const int r0 = wave * 16 + (lane >> 3);
    const int g0 = (lane & 7) ^ (r0 & 7);         // (r0+8)&7 == r0&7
    const unsigned short* Kbh = Kb + rowB * ND + headOff;
    const size_t offK0 = (size_t)r0 * ND + g0 * 8;
    const size_t offK1 = (size_t)(r0 + 8) * ND + g0 * 8;
    const size_t offV0 = (size_t)r0 * NT + g0 * 8;
    const size_t offV1 = (size_t)(r0 + 8) * NT + g0 * 8;

    const int swz = (l15 & 7);                    // read-side XOR key

    f32x4 o[4];
#pragma unroll
    for (int nt = 0; nt < 4; nt++) o[nt] = (f32x4)0.0f;
    float lacc = 0.0f;

    // prefetch tile 0 into buffer 0
    {
        unsigned short* dK = Ks + wave * 1024;
        unsigned short* dV = Vt + wave * 1024;
        load_lds16(Kbh + offK0, dK);
        load_lds16(Kbh + offK1, dK + 512);
        load_lds16(VT + offV0, dV);
        load_lds16(VT + offV1, dV + 512);
    }

    for (int kv = 0; kv < NT / 64; ++kv) {
        __syncthreads();   // drains vmcnt -> tile kv visible; buf[1-cur] free

        if (kv + 1 < NT / 64) {           // prefetch kv+1 into other buffer
            const unsigned short* kb = Kbh + (size_t)(kv + 1) * 64 * ND;
            const unsigned short* vb = VT + (kv + 1) * 64;
            unsigned short* dK = Ks + ((kv + 1) & 1) * 4096 + wave * 1024;
            unsigned short* dV = Vt + ((kv + 1) & 1) * 4096 + wave * 1024;
            load_lds16(kb + offK0, dK);
            load_lds16(kb + offK1, dK + 512);
            load_lds16(vb + offV0, dV);
            load_lds16(vb + offV1, dV + 512);
        }

        const unsigned short* KsC = Ks + (kv & 1) * 4096;
        const unsigned short* VtC = Vt + (kv & 1) * 4096;

        // S^T tiles + softmax -> packed bf16 P fragments (registers only)
        bs4 pk[4];
#pragma unroll
        for (int kt = 0; kt < 4; ++kt) {
            f32x4 st = (f32x4)0.0f;
#pragma unroll
            for (int ks = 0; ks < 2; ++ks) {
                short8 ak = *(const short8*)&KsC[(kt * 16 + l15) * 64
                                                 + (((ks * 4 + quad) ^ swz) * 8)];
                st = __builtin_amdgcn_mfma_f32_16x16x32_bf16(ak, aq[ks], st, 0, 0, 0);
            }
            float p0 = exp2f(st[0]), p1 = exp2f(st[1]);
            float p2 = exp2f(st[2]), p3 = exp2f(st[3]);
            lacc += (p0 + p1) + (p2 + p3);
            uint32_t lo = __builtin_amdgcn_perm(__float_as_uint(p1), __float_as_uint(p0),
                                                0x07060302u);   // {p0.hi16, p1.hi16}
            uint32_t hi = __builtin_amdgcn_perm(__float_as_uint(p3), __float_as_uint(p2),
                                                0x07060302u);
            union { uint32_t w[2]; bs4 v; } cvt;
            cvt.w[0] = lo; cvt.w[1] = hi;
            pk[kt] = cvt.v;
        }

        // O += P V  (A=pk from regs, B from swizzled Vt; k=16 keys per MFMA)
#pragma unroll
        for (int kt = 0; kt < 4; ++kt)
#pragma unroll
            for (int nt = 0; nt < 4; ++nt) {
                int cc = kt * 2 + (quad >> 1);
                bs4 vbf = *(const bs4*)&VtC[(nt * 16 + l15) * 64
                                            + ((cc ^ swz) * 8) + (quad & 1) * 4];
                o[nt] = __builtin_amdgcn_mfma_f32_16x16x16bf16_1k(pk[kt], vbf, o[nt], 0, 0, 0);
            }
    }

    // denominator: fold quads -> every lane holds full sum for q-row l15
    lacc += __shfl_xor(lacc, 16);
    lacc += __shfl_xor(lacc, 32);

#pragma unroll
    for (int reg = 0; reg < 4; ++reg) {
        float inv = 1.0f / __shfl(lacc, quad * 4 + reg);
        size_t row = rowB + qt * 64 + wave * 16 + quad * 4 + reg;
#pragma unroll
        for (int nt = 0; nt < 4; ++nt)
            Cb[row * ND + headOff + nt * 16 + l15] = f2b(o[nt][reg] * inv);
    }
}

// ---------------------------------------------------------------------------
extern "C" void kernel_launch(void* const* d_in, const int* in_sizes, int n_in,
                              void* d_out, int out_size, void* d_ws, size_t ws_size,
                              hipStream_t stream) {
    (void)in_sizes; (void)n_in; (void)out_size; (void)ws_size;
    const float* x  = (const float*)d_in[0];
    const float* Wq = (const float*)d_in[1];
    const float* bq = (const float*)d_in[2];
    const float* Wk = (const float*)d_in[3];
    const float* bk = (const float*)d_in[4];
    const float* Wv = (const float*)d_in[5];
    const float* bv = (const float*)d_in[6];
    const float* Wo = (const float*)d_in[7];
    const float* bo = (const float*)d_in[8];
    float* out = (float*)d_out;

    unsigned short* ws  = (unsigned short*)d_ws;
    unsigned short* xb  = ws;                   // 4194304 elems
    unsigned short* wqb = xb + 4194304;         // 4 x 262144 (wq,wk,wv,wo)
    unsigned short* Qb  = wqb + 4 * 262144;     // Q,K,VT,C 4194304 each
    unsigned short* Kb  = Qb + 4194304;
    unsigned short* VTb = Kb + 4194304;
    unsigned short* Cb  = VTb + 4194304;
    unsigned short* wob = wqb + 3 * 262144;

    convert_all<<<5120, 256, 0, stream>>>(x, Wq, Wk, Wv, Wo, ws);

    // fold 1/sqrt(dk) * log2(e) into Q so softmax uses exp2
    const float qscale = 0.125f * 1.44269504f;
    proj_gemm<<<dim3(4, 64, 3), 256, 0, stream>>>(xb, wqb, bq, bk, bv, Qb, VTb, qscale);
    attn_kernel<<<dim3(32, 8, 4), 256, 0, stream>>>(Qb, Kb, VTb, Cb);
    out_gemm<<<dim3(4, 128), 256, 0, stream>>>(Cb, wob, bo, out);
}

// Round 9
// 179.246 us; speedup vs baseline: 1.0065x; 1.0065x over previous
//
#include <hip/hip_runtime.h>
#include <stdint.h>

#define NB 4
#define NT 2048
#define ND 512
#define NH 8
#define NDK 64
#define NM (NB*NT)   // 8192 rows

typedef __attribute__((ext_vector_type(8))) short short8;
typedef __attribute__((ext_vector_type(4))) short bs4;     // 4 bf16 (2 VGPR)
typedef __attribute__((ext_vector_type(4))) float f32x4;

// round-to-nearest-even fp32 -> bf16
__device__ __forceinline__ unsigned short f2b(float f) {
    union { float f; uint32_t u; } v; v.f = f;
    return (unsigned short)((v.u + 0x7FFFu + ((v.u >> 16) & 1u)) >> 16);
}

__device__ __forceinline__ void load_lds16(const void* g, void* l) {
    void* gn = const_cast<void*>(g);
    __builtin_amdgcn_global_load_lds((__attribute__((address_space(1))) void*)gn,
                                     (__attribute__((address_space(3))) void*)l,
                                     16, 0, 0);
}

// ---------------------------------------------------------------------------
// fp32 -> bf16 conversion of x + Wq,Wk,Wv,Wo, packed into ws.
// ---------------------------------------------------------------------------
__global__ void convert_all(const float* __restrict__ x,  const float* __restrict__ wq,
                            const float* __restrict__ wk, const float* __restrict__ wv,
                            const float* __restrict__ wo, unsigned short* __restrict__ dst) {
    size_t i = ((size_t)blockIdx.x * 256 + threadIdx.x) * 4;
    const float* src; size_t off;
    if (i < 4194304) { src = x; off = i; }
    else {
        size_t j = i - 4194304;
        src = (j < 262144) ? wq : (j < 524288) ? wk : (j < 786432) ? wv : wo;
        off = j & 262143;
    }
    f32x4 v = *(const f32x4*)(src + off);
    ushort4 r;
    r.x = f2b(v[0]); r.y = f2b(v[1]); r.z = f2b(v[2]); r.w = f2b(v[3]);
    *(ushort4*)(dst + i) = r;
}

// ---------------------------------------------------------------------------
// Projections. z=0: Q = x@Wq.T (scaled), z=1: K = x@Wk.T  -> row-major bf16.
// z=2: VT = Wv@x.T directly -> VT[(b*8+h)*64+d][t], coalesced along t.
// m97 structure: 128x128 tile, BK=32, 256 thr, global_load_lds staging.
// ---------------------------------------------------------------------------
__global__ __launch_bounds__(256, 3) void proj_gemm(
        const unsigned short* __restrict__ X,
        const unsigned short* __restrict__ Wbase,
        const float* __restrict__ bias0, const float* __restrict__ bias1,
        const float* __restrict__ bias2,
        unsigned short* __restrict__ Obase, unsigned short* __restrict__ VTb,
        float scale0) {
    const int z = blockIdx.z;
    const float* bias = (z == 0) ? bias0 : (z == 1 ? bias1 : bias2);
    const float scale = (z == 0) ? scale0 : 1.0f;

    int rowBase, colBase;
    const unsigned short *Ap, *Bp;
    if (z == 2) {   // A = Wv (rows=d), B = x (rows=t)
        rowBase = blockIdx.x * 128;  colBase = blockIdx.y * 128;
        Ap = Wbase + 2 * (ND * ND);  Bp = X;
    } else {        // A = x (rows=t), B = Wq/Wk (rows=d)
        rowBase = blockIdx.y * 128;  colBase = blockIdx.x * 128;
        Ap = X;                      Bp = Wbase + (size_t)z * (ND * ND);
    }

    __shared__ alignas(16) unsigned short ldsA[128 * 32];
    __shared__ alignas(16) unsigned short ldsW[128 * 32];

    const int tid = threadIdx.x;
    const int lane = tid & 63, wave = tid >> 6;
    const int quad = lane >> 4, l15 = lane & 15;
    const int wm = wave >> 1, wn = wave & 1;

    const int rS = wave * 16 + (lane >> 2);
    const int kS = (lane & 3) * 8;
    const unsigned short* gA = Ap + (size_t)(rowBase + rS) * ND + kS;
    const unsigned short* gW = Bp + (size_t)(colBase + rS) * ND + kS;
    unsigned short* lA = ldsA + wave * 512;
    unsigned short* lW = ldsW + wave * 512;

    f32x4 acc[4][4];
#pragma unroll
    for (int i = 0; i < 4; i++)
#pragma unroll
        for (int j = 0; j < 4; j++) acc[i][j] = (f32x4)0.0f;

    for (int kt = 0; kt < ND / 32; ++kt) {
        __syncthreads();
        load_lds16(gA,            lA);
        load_lds16(gA + 64 * ND,  lA + 2048);
        load_lds16(gW,            lW);
        load_lds16(gW + 64 * ND,  lW + 2048);
        gA += 32; gW += 32;
        __syncthreads();

        short8 af[4], bfm[4];
#pragma unroll
        for (int mt = 0; mt < 4; ++mt)
            af[mt] = *(const short8*)(ldsA + (wm * 64 + mt * 16 + l15) * 32 + quad * 8);
#pragma unroll
        for (int nt = 0; nt < 4; ++nt)
            bfm[nt] = *(const short8*)(ldsW + (wn * 64 + nt * 16 + l15) * 32 + quad * 8);
#pragma unroll
        for (int mt = 0; mt < 4; ++mt)
#pragma unroll
            for (int nt = 0; nt < 4; ++nt)
                acc[mt][nt] = __builtin_amdgcn_mfma_f32_16x16x32_bf16(
                    af[mt], bfm[nt], acc[mt][nt], 0, 0, 0);
    }

    if (z == 2) {
        const int bz = colBase >> 11;
        const int t0 = colBase & 2047;
        unsigned short* VTo = VTb + ((size_t)(bz * 512 + rowBase)) * NT + t0;
#pragma unroll
        for (int mt = 0; mt < 4; mt++)
#pragma unroll
            for (int reg = 0; reg < 4; reg++) {
                int m = wm * 64 + mt * 16 + quad * 4 + reg;
                float bm = bias[rowBase + m];
                unsigned short* dst = VTo + (size_t)m * NT + wn * 64 + l15;
#pragma unroll
                for (int nt = 0; nt < 4; nt++)
                    dst[nt * 16] = f2b(acc[mt][nt][reg] + bm);
            }
    } else {
        float biasr[4];
#pragma unroll
        for (int nt = 0; nt < 4; nt++)
            biasr[nt] = bias[colBase + wn * 64 + nt * 16 + l15];
        unsigned short* Oz = Obase + (size_t)z * ((size_t)NM * ND);
#pragma unroll
        for (int mt = 0; mt < 4; mt++) {
            int row = rowBase + wm * 64 + mt * 16 + quad * 4;
#pragma unroll
            for (int reg = 0; reg < 4; reg++) {
                unsigned short* dst = Oz + (size_t)(row + reg) * ND + colBase + wn * 64 + l15;
#pragma unroll
                for (int nt = 0; nt < 4; nt++)
                    dst[nt * 16] = f2b((acc[mt][nt][reg] + biasr[nt]) * scale);
            }
        }
    }
}

// ---------------------------------------------------------------------------
// Output projection (fp32 out): 64x128 tile, 2x2 wave grid (32x64 per wave)
// -> 6 LDS reads per 8 MFMA per wave-iter. grid (4, 128) = 512 blocks.
// ---------------------------------------------------------------------------
__global__ __launch_bounds__(256, 4) void out_gemm(
        const unsigned short* __restrict__ A, const unsigned short* __restrict__ W,
        const float* __restrict__ bias, float* __restrict__ OF) {
    __shared__ alignas(16) unsigned short ldsA[64 * 32];
    __shared__ alignas(16) unsigned short ldsW[128 * 32];

    const int tid = threadIdx.x;
    const int lane = tid & 63, wave = tid >> 6;
    const int quad = lane >> 4, l15 = lane & 15;
    const int wm = wave >> 1, wn = wave & 1;
    const int rowBase = blockIdx.y * 64;
    const int colBase = blockIdx.x * 128;

    const int rW = wave * 16 + (lane >> 2);
    const int kS = (lane & 3) * 8;
    const unsigned short* gA = A + (size_t)(rowBase + rW) * ND + kS;
    const unsigned short* gW = W + (size_t)(colBase + rW) * ND + kS;
    unsigned short* lA = ldsA + wave * 512;
    unsigned short* lW = ldsW + wave * 512;

    f32x4 acc[2][4];
#pragma unroll
    for (int mt = 0; mt < 2; mt++)
#pragma unroll
        for (int nt = 0; nt < 4; nt++) acc[mt][nt] = (f32x4)0.0f;

    for (int kt = 0; kt < ND / 32; ++kt) {
        __syncthreads();
        load_lds16(gA,           lA);
        load_lds16(gW,           lW);
        load_lds16(gW + 64 * ND, lW + 2048);
        gA += 32; gW += 32;
        __syncthreads();

        short8 af[2], bfm[4];
#pragma unroll
        for (int mt = 0; mt < 2; ++mt)
            af[mt] = *(const short8*)(ldsA + (wm * 32 + mt * 16 + l15) * 32 + quad * 8);
#pragma unroll
        for (int nt = 0; nt < 4; ++nt)
            bfm[nt] = *(const short8*)(ldsW + (wn * 64 + nt * 16 + l15) * 32 + quad * 8);
#pragma unroll
        for (int mt = 0; mt < 2; ++mt)
#pragma unroll
            for (int nt = 0; nt < 4; ++nt)
                acc[mt][nt] = __builtin_amdgcn_mfma_f32_16x16x32_bf16(
                    af[mt], bfm[nt], acc[mt][nt], 0, 0, 0);
    }

    float biasr[4];
#pragma unroll
    for (int nt = 0; nt < 4; nt++)
        biasr[nt] = bias[colBase + wn * 64 + nt * 16 + l15];

#pragma unroll
    for (int mt = 0; mt < 2; mt++)
#pragma unroll
        for (int reg = 0; reg < 4; reg++) {
            int row = rowBase + wm * 32 + mt * 16 + quad * 4 + reg;
            float* dst = OF + (size_t)row * ND + colBase + wn * 64 + l15;
#pragma unroll
            for (int nt = 0; nt < 4; nt++)
                dst[nt * 16] = acc[mt][nt][reg] + biasr[nt];
        }
}

// ---------------------------------------------------------------------------
// Flash attention v8 — v6 single-buffer structure + hoisted LDS read bases.
// grid (32,8,4)=1024 blocks (4/CU), 256 thr; wave w owns q-rows [w*16,w*16+16)
// x all 64 keys. XOR-swizzled chunk layout: LDS chunk (r,p) holds global
// chunk p^(r&7); DMA deposits contiguous (zero write conflicts).
// All lane-variable LDS read addresses (2 ak bases, 4 vbf bases) are computed
// ONCE before the loop; in-loop reads use 16-bit immediate offsets only.
// S^T trick keeps P in registers (v5); barrier drain hidden by 4 blocks/CU.
// ---------------------------------------------------------------------------
__global__ __launch_bounds__(256, 4) void attn_kernel(
        const unsigned short* __restrict__ Qb, const unsigned short* __restrict__ Kb,
        const unsigned short* __restrict__ VTb, unsigned short* __restrict__ Cb) {
    const int qt = blockIdx.x, h = blockIdx.y, b = blockIdx.z;
    __shared__ alignas(16) unsigned short Ks[64 * 64];
    __shared__ alignas(16) unsigned short Vt[64 * 64];   // Vt[d][key], swizzled

    const int tid = threadIdx.x, lane = tid & 63, wave = tid >> 6;
    const int quad = lane >> 4, l15 = lane & 15;
    const size_t headOff = (size_t)h * NDK;
    const size_t rowB = (size_t)b * NT;
    const unsigned short* VT = VTb + (size_t)(b * NH + h) * ((size_t)NDK * NT);

    // Q fragments (B-operand of S^T MFMA): lane holds Q[q=l15][k=quad*8+j]
    short8 aq[2];
#pragma unroll
    for (int ks = 0; ks < 2; ++ks)
        aq[ks] = *(const short8*)(Qb + (rowB + qt * 64 + wave * 16 + l15) * ND
                                  + headOff + ks * 32 + quad * 8);

    // staging lane constants: call c covers rows wave*16+c*8+(lane>>3)
    const int r0 = wave * 16 + (lane >> 3);
    const int g0 = (lane & 7) ^ (r0 & 7);         // (r0+8)&7 == r0&7
    const unsigned short* Kbh = Kb + rowB * ND + headOff;
    const unsigned short* gK0 = Kbh + (size_t)r0 * ND + g0 * 8;
    const unsigned short* gK1 = Kbh + (size_t)(r0 + 8) * ND + g0 * 8;
    const unsigned short* gV0 = VT + (size_t)r0 * NT + g0 * 8;
    const unsigned short* gV1 = VT + (size_t)(r0 + 8) * NT + g0 * 8;
    unsigned short* ldsK = Ks + wave * 1024;      // c=0 dest; c=1 at +512
    unsigned short* ldsV = Vt + wave * 1024;

    // hoisted LDS read base pointers (lane-variable, loop-invariant)
    const int swz = l15 & 7;
    const int qh = quad >> 1, qlo = quad & 1;
    const unsigned short* kb0 = Ks + l15 * 64 + ((quad ^ swz) * 8);
    const unsigned short* kb1 = Ks + l15 * 64 + (((4 + quad) ^ swz) * 8);
    const unsigned short* vbp[4];
#pragma unroll
    for (int kt = 0; kt < 4; ++kt)
        vbp[kt] = Vt + l15 * 64 + (((kt * 2 + qh) ^ swz) * 8) + qlo * 4;

    f32x4 o[4];
#pragma unroll
    for (int nt = 0; nt < 4; nt++) o[nt] = (f32x4)0.0f;
    float lacc = 0.0f;

    for (int kv = 0; kv < NT / 64; ++kv) {
        __syncthreads();                  // prior iter done reading Ks/Vt
        load_lds16(gK0, ldsK);
        load_lds16(gK1, ldsK + 512);
        load_lds16(gV0, ldsV);
        load_lds16(gV1, ldsV + 512);
        gK0 += 64 * ND; gK1 += 64 * ND; gV0 += 64; gV1 += 64;
        __syncthreads();                  // vmcnt(0) drained -> tiles visible

        // S^T tiles + softmax -> packed bf16 P fragments (registers only)
        bs4 pk[4];
#pragma unroll
        for (int kt = 0; kt < 4; ++kt) {
            f32x4 st = (f32x4)0.0f;
            st = __builtin_amdgcn_mfma_f32_16x16x32_bf16(
                *(const short8*)(kb0 + kt * 1024), aq[0], st, 0, 0, 0);
            st = __builtin_amdgcn_mfma_f32_16x16x32_bf16(
                *(const short8*)(kb1 + kt * 1024), aq[1], st, 0, 0, 0);
            float p0 = exp2f(st[0]), p1 = exp2f(st[1]);
            float p2 = exp2f(st[2]), p3 = exp2f(st[3]);
            lacc += (p0 + p1) + (p2 + p3);
            uint32_t lo = __builtin_amdgcn_perm(__float_as_uint(p1), __float_as_uint(p0),
                                                0x07060302u);   // {p0.hi16, p1.hi16}
            uint32_t hi = __builtin_amdgcn_perm(__float_as_uint(p3), __float_as_uint(p2),
                                                0x07060302u);
            union { uint32_t w[2]; bs4 v; } cvt;
            cvt.w[0] = lo; cvt.w[1] = hi;
            pk[kt] = cvt.v;
        }

        // O += P V  (A=pk from regs, B from swizzled Vt; k=16 keys per MFMA)
#pragma unroll
        for (int kt = 0; kt < 4; ++kt)
#pragma unroll
            for (int nt = 0; nt < 4; ++nt)
                o[nt] = __builtin_amdgcn_mfma_f32_16x16x16bf16_1k(
                    pk[kt], *(const bs4*)(vbp[kt] + nt * 1024), o[nt], 0, 0, 0);
    }

    // denominator: fold quads -> every lane holds full sum for q-row l15
    lacc += __shfl_xor(lacc, 16);
    lacc += __shfl_xor(lacc, 32);

#pragma unroll
    for (int reg = 0; reg < 4; ++reg) {
        float inv = 1.0f / __shfl(lacc, quad * 4 + reg);
        size_t row = rowB + qt * 64 + wave * 16 + quad * 4 + reg;
#pragma unroll
        for (int nt = 0; nt < 4; ++nt)
            Cb[row * ND + headOff + nt * 16 + l15] = f2b(o[nt][reg] * inv);
    }
}

// ---------------------------------------------------------------------------
extern "C" void kernel_launch(void* const* d_in, const int* in_sizes, int n_in,
                              void* d_out, int out_size, void* d_ws, size_t ws_size,
                              hipStream_t stream) {
    (void)in_sizes; (void)n_in; (void)out_size; (void)ws_size;
    const float* x  = (const float*)d_in[0];
    const float* Wq = (const float*)d_in[1];
    const float* bq = (const float*)d_in[2];
    const float* Wk = (const float*)d_in[3];
    const float* bk = (const float*)d_in[4];
    const float* Wv = (const float*)d_in[5];
    const float* bv = (const float*)d_in[6];
    const float* Wo = (const float*)d_in[7];
    const float* bo = (const float*)d_in[8];
    float* out = (float*)d_out;

    unsigned short* ws  = (unsigned short*)d_ws;
    unsigned short* xb  = ws;                   // 4194304 elems
    unsigned short* wqb = xb + 4194304;         // 4 x 262144 (wq,wk,wv,wo)
    unsigned short* Qb  = wqb + 4 * 262144;     // Q,K,VT,C 4194304 each
    unsigned short* Kb  = Qb + 4194304;
    unsigned short* VTb = Kb + 4194304;
    unsigned short* Cb  = VTb + 4194304;
    unsigned short* wob = wqb + 3 * 262144;

    convert_all<<<5120, 256, 0, stream>>>(x, Wq, Wk, Wv, Wo, ws);

    // fold 1/sqrt(dk) * log2(e) into Q so softmax uses exp2
    const float qscale = 0.125f * 1.44269504f;
    proj_gemm<<<dim3(4, 64, 3), 256, 0, stream>>>(xb, wqb, bq, bk, bv, Qb, VTb, qscale);
    attn_kernel<<<dim3(32, 8, 4), 256, 0, stream>>>(Qb, Kb, VTb, Cb);
    out_gemm<<<dim3(4, 128), 256, 0, stream>>>(Cb, wob, bo, out);
}